// Round 8
// baseline (796.108 us; speedup 1.0000x reference)
//
#include <hip/hip_runtime.h>
#include <hip/hip_bf16.h>

// GCN: 3x GraphConv(norm='both') + 4->2 linear + softmax.
// Round 8: round-7 two-level counting-sort partition, with the gather loops
// unrolled 4x (4 independent P->H load chains per lane) to raise memory-level
// parallelism in the latency-bound random H[src] reads.

#define BT 256
#define BTL 1024
#define LOGW 9
#define NPB 512             // fine bucket (gather LDS acc)
#define LOGC 12
#define CNPB 4096           // coarse bucket
#define KCMAX 256
#define CH 65536            // edges per histC/rankC block

// ---------------- coarse partition ----------------

__global__ void histC_kernel(const int* __restrict__ src, const int* __restrict__ dst,
                             int* __restrict__ M1, int* __restrict__ M2,
                             int E, int KC, int NBLK) {
    __shared__ int h1[KCMAX];
    __shared__ int h2[KCMAX];
    for (int l = threadIdx.x; l < KC; l += BTL) { h1[l] = 0; h2[l] = 0; }
    __syncthreads();
    int base = blockIdx.x * CH;
    int lim = min(E - base, CH);
    for (int j = threadIdx.x; j < lim; j += BTL) {
        atomicAdd(&h1[dst[base + j] >> LOGC], 1);
        atomicAdd(&h2[src[base + j] >> LOGC], 1);
    }
    __syncthreads();
    for (int l = threadIdx.x; l < KC; l += BTL) {
        M1[(size_t)l * NBLK + blockIdx.x] = h1[l];
        M2[(size_t)l * NBLK + blockIdx.x] = h2[l];
    }
}

// One wave per coarse bucket: exclusive scan along block axis (in place), row sum out.
__global__ void rowscan_kernel(int* __restrict__ M1, int* __restrict__ M2,
                               int* __restrict__ bsum1, int* __restrict__ bsum2, int NBLK) {
    int b = blockIdx.x, lane = threadIdx.x;   // 64 threads
    size_t rb = (size_t)b * NBLK;
    int carry = 0;
    for (int base = 0; base < NBLK; base += 64) {
        int idx = base + lane;
        int v = (idx < NBLK) ? M1[rb + idx] : 0;
        int s = v;
        #pragma unroll
        for (int o = 1; o < 64; o <<= 1) { int u = __shfl_up(s, o); if (lane >= o) s += u; }
        if (idx < NBLK) M1[rb + idx] = carry + s - v;
        carry += __shfl(s, 63);
    }
    if (lane == 0) bsum1[b] = carry;
    carry = 0;
    for (int base = 0; base < NBLK; base += 64) {
        int idx = base + lane;
        int v = (idx < NBLK) ? M2[rb + idx] : 0;
        int s = v;
        #pragma unroll
        for (int o = 1; o < 64; o <<= 1) { int u = __shfl_up(s, o); if (lane >= o) s += u; }
        if (idx < NBLK) M2[rb + idx] = carry + s - v;
        carry += __shfl(s, 63);
    }
    if (lane == 0) bsum2[b] = carry;
}

// Single block, 256 threads: exclusive scan of both coarse-total arrays (KC <= 256).
__global__ void scanC_kernel(const int* __restrict__ bs1, int* __restrict__ cb1,
                             const int* __restrict__ bs2, int* __restrict__ cb2,
                             int* __restrict__ bbase1, int KC) {
    __shared__ int wt[4];
    int t = threadIdx.x, lane = t & 63, w = t >> 6;

    int v = (t < KC) ? bs1[t] : 0;
    int s = v;
    #pragma unroll
    for (int o = 1; o < 64; o <<= 1) { int u = __shfl_up(s, o); if (lane >= o) s += u; }
    if (lane == 63) wt[w] = s;
    __syncthreads();
    int wpre = 0;
    for (int j = 0; j < w; ++j) wpre += wt[j];
    if (t < KC) cb1[t] = wpre + s - v;
    if (t == 255) { int tot = wpre + s; cb1[KC] = tot; bbase1[8 * KC] = tot; }
    __syncthreads();

    v = (t < KC) ? bs2[t] : 0;
    s = v;
    #pragma unroll
    for (int o = 1; o < 64; o <<= 1) { int u = __shfl_up(s, o); if (lane >= o) s += u; }
    if (lane == 63) wt[w] = s;
    __syncthreads();
    wpre = 0;
    for (int j = 0; j < w; ++j) wpre += wt[j];
    if (t < KC) cb2[t] = wpre + s - v;
    if (t == 255) cb2[KC] = wpre + s;
}

// Coarse rank: PC = (src<<12)|dst_local (unsigned) by dst-coarse; SC = src by src-coarse.
__global__ void rankC_kernel(const int* __restrict__ src, const int* __restrict__ dst,
                             const int* __restrict__ M1, const int* __restrict__ M2,
                             const int* __restrict__ cb1, const int* __restrict__ cb2,
                             unsigned int* __restrict__ PC, int* __restrict__ SC,
                             int E, int KC, int NBLK) {
    __shared__ int c1[KCMAX];
    __shared__ int c2[KCMAX];
    int blk = blockIdx.x;
    for (int l = threadIdx.x; l < KC; l += BTL) {
        c1[l] = cb1[l] + M1[(size_t)l * NBLK + blk];
        c2[l] = cb2[l] + M2[(size_t)l * NBLK + blk];
    }
    __syncthreads();
    int base = blk * CH;
    int lim = min(E - base, CH);
    for (int j = threadIdx.x; j < lim; j += BTL) {
        int s = src[base + j], d = dst[base + j];
        int p = atomicAdd(&c1[d >> LOGC], 1);
        PC[p] = ((unsigned int)s << LOGC) | (unsigned int)(d & (CNPB - 1));
        int q = atomicAdd(&c2[s >> LOGC], 1);
        SC[q] = s;
    }
}

// Out-degrees: one block per coarse src bucket, 4096-counter LDS histogram.
__global__ void sdegC_kernel(const int* __restrict__ SC, const int* __restrict__ cb2,
                             const float* __restrict__ x,
                             float* __restrict__ ns, float* __restrict__ sx, int N) {
    __shared__ int h[CNPB];
    int b = blockIdx.x;
    for (int l = threadIdx.x; l < CNPB; l += BTL) h[l] = 0;
    __syncthreads();
    int gb = cb2[b], ge = cb2[b + 1];
    for (int j = gb + threadIdx.x; j < ge; j += BTL) atomicAdd(&h[SC[j] & (CNPB - 1)], 1);
    __syncthreads();
    int vb = b << LOGC;
    for (int l = threadIdx.x; l < CNPB; l += BTL) {
        int v = vb + l;
        if (v < N) {
            int d = h[l];
            float nsv = d > 0 ? rsqrtf((float)d) : 0.f;
            ns[v] = nsv;
            sx[v] = x[v] * nsv;
        }
    }
}

// Fine pass: one block per coarse dst bucket. Ballot-rank its segment into the
// 8 fine (512-node) sub-buckets; emit P = (src<<9)|dst_local9 (unsigned) + bbase1.
__global__ void fine_kernel(const unsigned int* __restrict__ PC, const int* __restrict__ cb1,
                            unsigned int* __restrict__ P, int* __restrict__ bbase1) {
    __shared__ int h[8];
    __shared__ int cur[8];
    int b = blockIdx.x;
    int gb = cb1[b], ge = cb1[b + 1];
    int t = threadIdx.x, lane = t & 63;
    if (t < 8) h[t] = 0;
    __syncthreads();
    int iters = (ge - gb + BTL - 1) / BTL;
    for (int it = 0; it < iters; ++it) {
        int j = gb + it * BTL + t;
        int myf = 8;
        if (j < ge) myf = (int)((PC[j] >> LOGW) & 7u);
        #pragma unroll
        for (int f = 0; f < 8; ++f) {
            unsigned long long m = __ballot(myf == f);
            if (m && lane == (__ffsll((long long)m) - 1))
                atomicAdd(&h[f], (int)__popcll(m));
        }
    }
    __syncthreads();
    if (t == 0) {
        int run = gb;
        #pragma unroll
        for (int f = 0; f < 8; ++f) { cur[f] = run; bbase1[b * 8 + f] = run; run += h[f]; }
    }
    __syncthreads();
    for (int it = 0; it < iters; ++it) {
        int j = gb + it * BTL + t;
        int myf = 8;
        unsigned int val = 0;
        if (j < ge) { val = PC[j]; myf = (int)((val >> LOGW) & 7u); }
        #pragma unroll
        for (int f = 0; f < 8; ++f) {
            unsigned long long m = __ballot(myf == f);
            if (m) {
                int leader = __ffsll((long long)m) - 1;
                int base;
                if (lane == leader) base = atomicAdd(&cur[f], (int)__popcll(m));
                base = __shfl(base, leader);
                if (myf == f) {
                    int below = (int)__popcll(m & ((1ull << lane) - 1));
                    P[base + below] = ((val >> LOGC) << LOGW) | (val & (NPB - 1));
                }
            }
        }
    }
}

// ---------------- fused gathers (NPB = 512, 4x-unrolled MLP) ----------------

__global__ void g1_kernel(const unsigned int* __restrict__ P, const int* __restrict__ bbase1,
                          const float* __restrict__ sx, const float* __restrict__ ns,
                          float* __restrict__ nd,
                          const float* __restrict__ W1, const float* __restrict__ b1,
                          const float* __restrict__ W2, float4* __restrict__ A, int N) {
    __shared__ float acc[NPB];
    __shared__ int cnt[NPB];
    int b = blockIdx.x;
    for (int l = threadIdx.x; l < NPB; l += BT) { acc[l] = 0.f; cnt[l] = 0; }
    __syncthreads();
    int gb = bbase1[b], ge = bbase1[b + 1];
    int j = gb + threadIdx.x;
    for (; j + 3 * BT < ge; j += 4 * BT) {
        unsigned int v0 = P[j], v1 = P[j + BT], v2 = P[j + 2 * BT], v3 = P[j + 3 * BT];
        float s0 = sx[v0 >> LOGW];
        float s1 = sx[v1 >> LOGW];
        float s2 = sx[v2 >> LOGW];
        float s3 = sx[v3 >> LOGW];
        int l0 = (int)(v0 & (NPB - 1)), l1 = (int)(v1 & (NPB - 1));
        int l2 = (int)(v2 & (NPB - 1)), l3 = (int)(v3 & (NPB - 1));
        atomicAdd(&acc[l0], s0); atomicAdd(&cnt[l0], 1);
        atomicAdd(&acc[l1], s1); atomicAdd(&cnt[l1], 1);
        atomicAdd(&acc[l2], s2); atomicAdd(&cnt[l2], 1);
        atomicAdd(&acc[l3], s3); atomicAdd(&cnt[l3], 1);
    }
    for (; j < ge; j += BT) {
        unsigned int val = P[j];
        int l = (int)(val & (NPB - 1));
        atomicAdd(&acc[l], sx[val >> LOGW]);
        atomicAdd(&cnt[l], 1);
    }
    __syncthreads();
    int vb = b << LOGW;
    for (int l = threadIdx.x; l < NPB; l += BT) {
        int v = vb + l;
        if (v < N) {
            int hh = cnt[l];
            float ndv = hh > 0 ? rsqrtf((float)hh) : 0.f;
            nd[v] = ndv;
            float tt = acc[l] * ndv;
            float nsv = ns[v];
            float x0 = fmaxf(tt * W1[0] + b1[0], 0.f) * nsv;
            float x1 = fmaxf(tt * W1[1] + b1[1], 0.f) * nsv;
            float x2 = fmaxf(tt * W1[2] + b1[2], 0.f) * nsv;
            float x3 = fmaxf(tt * W1[3] + b1[3], 0.f) * nsv;
            float4 o;
            o.x = x0*W2[0] + x1*W2[4] + x2*W2[8]  + x3*W2[12];
            o.y = x0*W2[1] + x1*W2[5] + x2*W2[9]  + x3*W2[13];
            o.z = x0*W2[2] + x1*W2[6] + x2*W2[10] + x3*W2[14];
            o.w = x0*W2[3] + x1*W2[7] + x2*W2[11] + x3*W2[15];
            A[v] = o;
        }
    }
}

__global__ void g4_kernel(const unsigned int* __restrict__ P, const int* __restrict__ bbase1,
                          const float4* __restrict__ H, const float* __restrict__ ns,
                          const float* __restrict__ nd,
                          const float* __restrict__ bb, const float* __restrict__ W,
                          float4* __restrict__ out, int N) {
    __shared__ float acc[NPB * 4];
    int b = blockIdx.x;
    for (int l = threadIdx.x; l < NPB * 4; l += BT) acc[l] = 0.f;
    __syncthreads();
    int gb = bbase1[b], ge = bbase1[b + 1];
    int j = gb + threadIdx.x;
    for (; j + 3 * BT < ge; j += 4 * BT) {
        unsigned int v0 = P[j], v1 = P[j + BT], v2 = P[j + 2 * BT], v3 = P[j + 3 * BT];
        float4 h0 = H[v0 >> LOGW];
        float4 h1 = H[v1 >> LOGW];
        float4 h2 = H[v2 >> LOGW];
        float4 h3 = H[v3 >> LOGW];
        int l0 = (int)(v0 & (NPB - 1)) * 4, l1 = (int)(v1 & (NPB - 1)) * 4;
        int l2 = (int)(v2 & (NPB - 1)) * 4, l3 = (int)(v3 & (NPB - 1)) * 4;
        atomicAdd(&acc[l0+0], h0.x); atomicAdd(&acc[l0+1], h0.y);
        atomicAdd(&acc[l0+2], h0.z); atomicAdd(&acc[l0+3], h0.w);
        atomicAdd(&acc[l1+0], h1.x); atomicAdd(&acc[l1+1], h1.y);
        atomicAdd(&acc[l1+2], h1.z); atomicAdd(&acc[l1+3], h1.w);
        atomicAdd(&acc[l2+0], h2.x); atomicAdd(&acc[l2+1], h2.y);
        atomicAdd(&acc[l2+2], h2.z); atomicAdd(&acc[l2+3], h2.w);
        atomicAdd(&acc[l3+0], h3.x); atomicAdd(&acc[l3+1], h3.y);
        atomicAdd(&acc[l3+2], h3.z); atomicAdd(&acc[l3+3], h3.w);
    }
    for (; j < ge; j += BT) {
        unsigned int val = P[j];
        float4 v = H[val >> LOGW];
        int l4 = (int)(val & (NPB - 1)) * 4;
        atomicAdd(&acc[l4 + 0], v.x);
        atomicAdd(&acc[l4 + 1], v.y);
        atomicAdd(&acc[l4 + 2], v.z);
        atomicAdd(&acc[l4 + 3], v.w);
    }
    __syncthreads();
    int vb = b << LOGW;
    for (int l = threadIdx.x; l < NPB; l += BT) {
        int v = vb + l;
        if (v < N) {
            float ndv = nd[v], nsv = ns[v];
            float x0 = fmaxf(acc[l*4+0] * ndv + bb[0], 0.f) * nsv;
            float x1 = fmaxf(acc[l*4+1] * ndv + bb[1], 0.f) * nsv;
            float x2 = fmaxf(acc[l*4+2] * ndv + bb[2], 0.f) * nsv;
            float x3 = fmaxf(acc[l*4+3] * ndv + bb[3], 0.f) * nsv;
            float4 o;
            o.x = x0*W[0] + x1*W[4] + x2*W[8]  + x3*W[12];
            o.y = x0*W[1] + x1*W[5] + x2*W[9]  + x3*W[13];
            o.z = x0*W[2] + x1*W[6] + x2*W[10] + x3*W[14];
            o.w = x0*W[3] + x1*W[7] + x2*W[11] + x3*W[15];
            out[v] = o;
        }
    }
}

__global__ void gF_kernel(const unsigned int* __restrict__ P, const int* __restrict__ bbase1,
                          const float4* __restrict__ H, const float* __restrict__ nd,
                          const float* __restrict__ bb, const float* __restrict__ Wl,
                          const float* __restrict__ bl, float2* __restrict__ out, int N) {
    __shared__ float acc[NPB * 4];
    int b = blockIdx.x;
    for (int l = threadIdx.x; l < NPB * 4; l += BT) acc[l] = 0.f;
    __syncthreads();
    int gb = bbase1[b], ge = bbase1[b + 1];
    int j = gb + threadIdx.x;
    for (; j + 3 * BT < ge; j += 4 * BT) {
        unsigned int v0 = P[j], v1 = P[j + BT], v2 = P[j + 2 * BT], v3 = P[j + 3 * BT];
        float4 h0 = H[v0 >> LOGW];
        float4 h1 = H[v1 >> LOGW];
        float4 h2 = H[v2 >> LOGW];
        float4 h3 = H[v3 >> LOGW];
        int l0 = (int)(v0 & (NPB - 1)) * 4, l1 = (int)(v1 & (NPB - 1)) * 4;
        int l2 = (int)(v2 & (NPB - 1)) * 4, l3 = (int)(v3 & (NPB - 1)) * 4;
        atomicAdd(&acc[l0+0], h0.x); atomicAdd(&acc[l0+1], h0.y);
        atomicAdd(&acc[l0+2], h0.z); atomicAdd(&acc[l0+3], h0.w);
        atomicAdd(&acc[l1+0], h1.x); atomicAdd(&acc[l1+1], h1.y);
        atomicAdd(&acc[l1+2], h1.z); atomicAdd(&acc[l1+3], h1.w);
        atomicAdd(&acc[l2+0], h2.x); atomicAdd(&acc[l2+1], h2.y);
        atomicAdd(&acc[l2+2], h2.z); atomicAdd(&acc[l2+3], h2.w);
        atomicAdd(&acc[l3+0], h3.x); atomicAdd(&acc[l3+1], h3.y);
        atomicAdd(&acc[l3+2], h3.z); atomicAdd(&acc[l3+3], h3.w);
    }
    for (; j < ge; j += BT) {
        unsigned int val = P[j];
        float4 v = H[val >> LOGW];
        int l4 = (int)(val & (NPB - 1)) * 4;
        atomicAdd(&acc[l4 + 0], v.x);
        atomicAdd(&acc[l4 + 1], v.y);
        atomicAdd(&acc[l4 + 2], v.z);
        atomicAdd(&acc[l4 + 3], v.w);
    }
    __syncthreads();
    int vb = b << LOGW;
    for (int l = threadIdx.x; l < NPB; l += BT) {
        int v = vb + l;
        if (v < N) {
            float ndv = nd[v];
            float x0 = acc[l*4+0] * ndv + bb[0];
            float x1 = acc[l*4+1] * ndv + bb[1];
            float x2 = acc[l*4+2] * ndv + bb[2];
            float x3 = acc[l*4+3] * ndv + bb[3];
            float z0 = x0*Wl[0] + x1*Wl[2] + x2*Wl[4] + x3*Wl[6] + bl[0];
            float z1 = x0*Wl[1] + x1*Wl[3] + x2*Wl[5] + x3*Wl[7] + bl[1];
            float m  = fmaxf(z0, z1);
            float e0 = expf(z0 - m), e1 = expf(z1 - m);
            float inv = 1.f / (e0 + e1);
            out[v] = make_float2(e0 * inv, e1 * inv);
        }
    }
}

// ---------------- round-2 fallback (atomic-cursor CSR) ----------------

__global__ void count_kernel(const int* __restrict__ src, const int* __restrict__ dst,
                             int* __restrict__ degs, int* __restrict__ degd, int E) {
    int i = blockIdx.x * blockDim.x + threadIdx.x;
    if (i < E) { atomicAdd(&degs[src[i]], 1); atomicAdd(&degd[dst[i]], 1); }
}

__global__ void finalize_alloc_kernel(const int* __restrict__ degs, const int* __restrict__ degd,
                                      const float* __restrict__ x,
                                      float* __restrict__ ns, float* __restrict__ nd,
                                      float* __restrict__ sx, int* __restrict__ start,
                                      int* __restrict__ cursor, int N) {
    int i = blockIdx.x * blockDim.x + threadIdx.x;
    int lane = threadIdx.x & 63;
    int dd = 0;
    if (i < N) {
        int ds = degs[i];
        float nsv = ds > 0 ? rsqrtf((float)ds) : 0.f;
        ns[i] = nsv;
        dd = degd[i];
        nd[i] = dd > 0 ? rsqrtf((float)dd) : 0.f;
        sx[i] = x[i] * nsv;
    }
    int pre = dd;
    #pragma unroll
    for (int off = 1; off < 64; off <<= 1) {
        int t = __shfl_up(pre, off);
        if (lane >= off) pre += t;
    }
    int total = __shfl(pre, 63);
    int base = 0;
    if (lane == 63 && total > 0) base = atomicAdd(cursor, total);
    base = __shfl(base, 63);
    if (i < N) start[i] = base + pre - dd;
}

__global__ void fill_kernel(const int* __restrict__ src, const int* __restrict__ dst,
                            int* __restrict__ start, int* __restrict__ eidx, int E) {
    int i = blockIdx.x * blockDim.x + threadIdx.x;
    if (i < E) {
        int p = atomicAdd(&start[dst[i]], 1);
        eidx[p] = src[i];
    }
}

__global__ void fb_g1(const float* __restrict__ sx, const int* __restrict__ eidx,
                      const int* __restrict__ endp, const int* __restrict__ deg,
                      const float* __restrict__ ns, const float* __restrict__ nd,
                      const float* __restrict__ W1, const float* __restrict__ b1,
                      const float* __restrict__ W2, float4* __restrict__ A, int N) {
    int i = blockIdx.x * blockDim.x + threadIdx.x;
    if (i >= N) return;
    int e = endp[i], d = deg[i];
    float sum = 0.f;
    for (int k = e - d; k < e; ++k) sum += sx[eidx[k]];
    float t = sum * nd[i];
    float nsv = ns[i];
    float x0 = fmaxf(t * W1[0] + b1[0], 0.f) * nsv;
    float x1 = fmaxf(t * W1[1] + b1[1], 0.f) * nsv;
    float x2 = fmaxf(t * W1[2] + b1[2], 0.f) * nsv;
    float x3 = fmaxf(t * W1[3] + b1[3], 0.f) * nsv;
    float4 o;
    o.x = x0*W2[0] + x1*W2[4] + x2*W2[8]  + x3*W2[12];
    o.y = x0*W2[1] + x1*W2[5] + x2*W2[9]  + x3*W2[13];
    o.z = x0*W2[2] + x1*W2[6] + x2*W2[10] + x3*W2[14];
    o.w = x0*W2[3] + x1*W2[7] + x2*W2[11] + x3*W2[15];
    A[i] = o;
}

__global__ void fb_g4(const float4* __restrict__ H, const int* __restrict__ eidx,
                      const int* __restrict__ endp, const int* __restrict__ deg,
                      const float* __restrict__ ns, const float* __restrict__ nd,
                      const float* __restrict__ b, const float* __restrict__ W,
                      float4* __restrict__ out, int N) {
    int i = blockIdx.x * blockDim.x + threadIdx.x;
    if (i >= N) return;
    int e = endp[i], d = deg[i];
    float s0 = 0.f, s1 = 0.f, s2 = 0.f, s3 = 0.f;
    for (int k = e - d; k < e; ++k) {
        float4 v = H[eidx[k]];
        s0 += v.x; s1 += v.y; s2 += v.z; s3 += v.w;
    }
    float nv = nd[i], nsv = ns[i];
    float x0 = fmaxf(s0 * nv + b[0], 0.f) * nsv;
    float x1 = fmaxf(s1 * nv + b[1], 0.f) * nsv;
    float x2 = fmaxf(s2 * nv + b[2], 0.f) * nsv;
    float x3 = fmaxf(s3 * nv + b[3], 0.f) * nsv;
    float4 o;
    o.x = x0*W[0] + x1*W[4] + x2*W[8]  + x3*W[12];
    o.y = x0*W[1] + x1*W[5] + x2*W[9]  + x3*W[13];
    o.z = x0*W[2] + x1*W[6] + x2*W[10] + x3*W[14];
    o.w = x0*W[3] + x1*W[7] + x2*W[11] + x3*W[15];
    out[i] = o;
}

__global__ void fb_gF(const float4* __restrict__ H, const int* __restrict__ eidx,
                      const int* __restrict__ endp, const int* __restrict__ deg,
                      const float* __restrict__ nd, const float* __restrict__ b,
                      const float* __restrict__ Wl, const float* __restrict__ bl,
                      float2* __restrict__ out, int N) {
    int i = blockIdx.x * blockDim.x + threadIdx.x;
    if (i >= N) return;
    int e = endp[i], d = deg[i];
    float s0 = 0.f, s1 = 0.f, s2 = 0.f, s3 = 0.f;
    for (int k = e - d; k < e; ++k) {
        float4 v = H[eidx[k]];
        s0 += v.x; s1 += v.y; s2 += v.z; s3 += v.w;
    }
    float nv = nd[i];
    float x0 = s0 * nv + b[0];
    float x1 = s1 * nv + b[1];
    float x2 = s2 * nv + b[2];
    float x3 = s3 * nv + b[3];
    float z0 = x0*Wl[0] + x1*Wl[2] + x2*Wl[4] + x3*Wl[6] + bl[0];
    float z1 = x0*Wl[1] + x1*Wl[3] + x2*Wl[5] + x3*Wl[7] + bl[1];
    float m  = fmaxf(z0, z1);
    float e0 = expf(z0 - m), e1 = expf(z1 - m);
    float inv = 1.f / (e0 + e1);
    out[i] = make_float2(e0 * inv, e1 * inv);
}

extern "C" void kernel_launch(void* const* d_in, const int* in_sizes, int n_in,
                              void* d_out, int out_size, void* d_ws, size_t ws_size,
                              hipStream_t stream) {
    const float* in_feat = (const float*)d_in[0];
    const int*   src     = (const int*)d_in[1];
    const int*   dst     = (const int*)d_in[2];
    const float* W1 = (const float*)d_in[3];
    const float* b1 = (const float*)d_in[4];
    const float* W2 = (const float*)d_in[5];
    const float* b2 = (const float*)d_in[6];
    const float* W3 = (const float*)d_in[7];
    const float* b3 = (const float*)d_in[8];
    const float* Wl = (const float*)d_in[9];
    const float* bl = (const float*)d_in[10];

    const int N = in_sizes[0];
    const int E = in_sizes[1];

    const int gridN = (N + BT - 1) / BT;
    const int gridE = (E + BT - 1) / BT;

    const int KC   = (N + CNPB - 1) >> LOGC;     // coarse buckets
    const int K    = (N + NPB - 1) >> LOGW;      // fine buckets
    const int NBLK = (E + CH - 1) / CH;
    const size_t uN = (size_t)N, uE = (size_t)E;

    // Workspace (4B units):
    //  ns[N] | nd[N] (M1,M2 alias here until g1) | sx[N] | ctr[3104]
    //  | R1[max(E,8N)]  (PC, then A(4N)+B(4N))
    //  | R2[E]          (SC, then P)
    const size_t CTRI = 257 * 4 + 8 * (size_t)KCMAX + 8;
    const size_t r1 = (uE > 8 * uN) ? uE : 8 * uN;
    const size_t need6 = (3 * uN + CTRI + r1 + uE) * 4;

    const bool ok6 = (ws_size >= need6) && (N <= (1 << 20)) && (KC <= KCMAX)
                     && (2 * (size_t)KC * NBLK <= uN);

    if (ok6) {
        float* ws   = (float*)d_ws;
        float* ns   = ws;
        float* nd   = ws + uN;
        float* sx   = ws + 2 * uN;
        int*   ctr  = (int*)(ws + 3 * uN);
        int* bs1    = ctr;
        int* bs2    = ctr + 257;
        int* cb1    = ctr + 514;
        int* cb2    = ctr + 771;
        int* bbase1 = ctr + 1028;
        int*   R1   = (int*)(ws + 3 * uN + CTRI);
        int*   R2   = R1 + r1;
        int*   M1   = (int*)nd;                  // dead until g1 writes nd
        int*   M2   = M1 + (size_t)KC * NBLK;
        unsigned int* PC = (unsigned int*)R1;
        int*   SC   = R2;
        unsigned int* P  = (unsigned int*)R2;    // fine pass overwrites SC
        float4* A   = (float4*)R1;               // PC dead after fine
        float4* B4  = (float4*)(R1 + 4 * uN);

        histC_kernel<<<NBLK, BTL, 0, stream>>>(src, dst, M1, M2, E, KC, NBLK);
        rowscan_kernel<<<KC, 64, 0, stream>>>(M1, M2, bs1, bs2, NBLK);
        scanC_kernel<<<1, 256, 0, stream>>>(bs1, cb1, bs2, cb2, bbase1, KC);
        rankC_kernel<<<NBLK, BTL, 0, stream>>>(src, dst, M1, M2, cb1, cb2, PC, SC, E, KC, NBLK);
        sdegC_kernel<<<KC, BTL, 0, stream>>>(SC, cb2, in_feat, ns, sx, N);
        fine_kernel<<<KC, BTL, 0, stream>>>(PC, cb1, P, bbase1);
        g1_kernel<<<K, BT, 0, stream>>>(P, bbase1, sx, ns, nd, W1, b1, W2, A, N);
        g4_kernel<<<K, BT, 0, stream>>>(P, bbase1, A, ns, nd, b2, W3, B4, N);
        gF_kernel<<<K, BT, 0, stream>>>(P, bbase1, B4, nd, b3, Wl, bl, (float2*)d_out, N);
        return;
    }

    // ---------- round-2 fallback ----------
    size_t need2 = (13 * uN + uE + 16) * 4;
    if (ws_size >= need2) {
        float* ws   = (float*)d_ws;
        float* ns   = ws;
        float* nd   = ws + uN;
        float* sx   = ws + 2 * uN;
        int*   deg  = (int*)(ws + 3 * uN);
        int*   start= (int*)(ws + 4 * uN);
        float4* A   = (float4*)(ws + 5 * uN);
        float4* B   = (float4*)(ws + 9 * uN);
        int*   eidx = (int*)(ws + 13 * uN);
        int*   cursor = eidx + uE;
        int*   degs = (int*)A;

        hipMemsetAsync(deg, 0, uN * sizeof(int), stream);
        hipMemsetAsync(degs, 0, uN * sizeof(int), stream);
        hipMemsetAsync(cursor, 0, sizeof(int), stream);
        count_kernel<<<gridE, BT, 0, stream>>>(src, dst, degs, deg, E);
        finalize_alloc_kernel<<<gridN, BT, 0, stream>>>(degs, deg, in_feat, ns, nd, sx, start, cursor, N);
        fill_kernel<<<gridE, BT, 0, stream>>>(src, dst, start, eidx, E);
        fb_g1<<<gridN, BT, 0, stream>>>(sx, eidx, start, deg, ns, nd, W1, b1, W2, A, N);
        fb_g4<<<gridN, BT, 0, stream>>>(A, eidx, start, deg, ns, nd, b2, W3, B, N);
        fb_gF<<<gridN, BT, 0, stream>>>(B, eidx, start, deg, nd, b3, Wl, bl, (float2*)d_out, N);
    }
}

// Round 9
// 750.335 us; speedup vs baseline: 1.0610x; 1.0610x over previous
//
#include <hip/hip_runtime.h>
#include <hip/hip_bf16.h>

// GCN: 3x GraphConv(norm='both') + 4->2 linear + softmax.
// Round 9: two-level counting-sort partition; fine pass now bins by
// (fine-dst, src-stripe) = 64 bins, so each fine bucket's edges are ordered
// by src stripe (8 stripes x 2MB of H). All resident gather blocks sweep
// stripes in near-lockstep -> instantaneous per-XCD read window ~= one
// stripe, which fits the 4MB L2 (attacks the 400MB L2-miss traffic that
// bounds g4/gF at ~2.4TB/s).

#define BT 256
#define BTL 1024
#define LOGW 9
#define NPB 512             // fine bucket (gather LDS acc)
#define LOGC 12
#define CNPB 4096           // coarse bucket
#define KCMAX 256
#define CH 65536            // edges per histC/rankC block
#define NBIN 64             // 8 fine-dst x 8 src-stripe

// ---------------- coarse partition ----------------

__global__ void histC_kernel(const int* __restrict__ src, const int* __restrict__ dst,
                             int* __restrict__ M1, int* __restrict__ M2,
                             int E, int KC, int NBLK) {
    __shared__ int h1[KCMAX];
    __shared__ int h2[KCMAX];
    for (int l = threadIdx.x; l < KC; l += BTL) { h1[l] = 0; h2[l] = 0; }
    __syncthreads();
    int base = blockIdx.x * CH;
    int lim = min(E - base, CH);
    for (int j = threadIdx.x; j < lim; j += BTL) {
        atomicAdd(&h1[dst[base + j] >> LOGC], 1);
        atomicAdd(&h2[src[base + j] >> LOGC], 1);
    }
    __syncthreads();
    for (int l = threadIdx.x; l < KC; l += BTL) {
        M1[(size_t)l * NBLK + blockIdx.x] = h1[l];
        M2[(size_t)l * NBLK + blockIdx.x] = h2[l];
    }
}

// One wave per coarse bucket: exclusive scan along block axis (in place), row sum out.
__global__ void rowscan_kernel(int* __restrict__ M1, int* __restrict__ M2,
                               int* __restrict__ bsum1, int* __restrict__ bsum2, int NBLK) {
    int b = blockIdx.x, lane = threadIdx.x;   // 64 threads
    size_t rb = (size_t)b * NBLK;
    int carry = 0;
    for (int base = 0; base < NBLK; base += 64) {
        int idx = base + lane;
        int v = (idx < NBLK) ? M1[rb + idx] : 0;
        int s = v;
        #pragma unroll
        for (int o = 1; o < 64; o <<= 1) { int u = __shfl_up(s, o); if (lane >= o) s += u; }
        if (idx < NBLK) M1[rb + idx] = carry + s - v;
        carry += __shfl(s, 63);
    }
    if (lane == 0) bsum1[b] = carry;
    carry = 0;
    for (int base = 0; base < NBLK; base += 64) {
        int idx = base + lane;
        int v = (idx < NBLK) ? M2[rb + idx] : 0;
        int s = v;
        #pragma unroll
        for (int o = 1; o < 64; o <<= 1) { int u = __shfl_up(s, o); if (lane >= o) s += u; }
        if (idx < NBLK) M2[rb + idx] = carry + s - v;
        carry += __shfl(s, 63);
    }
    if (lane == 0) bsum2[b] = carry;
}

// Single block, 256 threads: exclusive scan of both coarse-total arrays (KC <= 256).
__global__ void scanC_kernel(const int* __restrict__ bs1, int* __restrict__ cb1,
                             const int* __restrict__ bs2, int* __restrict__ cb2,
                             int* __restrict__ bbase1, int KC) {
    __shared__ int wt[4];
    int t = threadIdx.x, lane = t & 63, w = t >> 6;

    int v = (t < KC) ? bs1[t] : 0;
    int s = v;
    #pragma unroll
    for (int o = 1; o < 64; o <<= 1) { int u = __shfl_up(s, o); if (lane >= o) s += u; }
    if (lane == 63) wt[w] = s;
    __syncthreads();
    int wpre = 0;
    for (int j = 0; j < w; ++j) wpre += wt[j];
    if (t < KC) cb1[t] = wpre + s - v;
    if (t == 255) { int tot = wpre + s; cb1[KC] = tot; bbase1[8 * KC] = tot; }
    __syncthreads();

    v = (t < KC) ? bs2[t] : 0;
    s = v;
    #pragma unroll
    for (int o = 1; o < 64; o <<= 1) { int u = __shfl_up(s, o); if (lane >= o) s += u; }
    if (lane == 63) wt[w] = s;
    __syncthreads();
    wpre = 0;
    for (int j = 0; j < w; ++j) wpre += wt[j];
    if (t < KC) cb2[t] = wpre + s - v;
    if (t == 255) cb2[KC] = wpre + s;
}

// Coarse rank: PC = (src<<12)|dst_local (unsigned) by dst-coarse; SC = src by src-coarse.
__global__ void rankC_kernel(const int* __restrict__ src, const int* __restrict__ dst,
                             const int* __restrict__ M1, const int* __restrict__ M2,
                             const int* __restrict__ cb1, const int* __restrict__ cb2,
                             unsigned int* __restrict__ PC, int* __restrict__ SC,
                             int E, int KC, int NBLK) {
    __shared__ int c1[KCMAX];
    __shared__ int c2[KCMAX];
    int blk = blockIdx.x;
    for (int l = threadIdx.x; l < KC; l += BTL) {
        c1[l] = cb1[l] + M1[(size_t)l * NBLK + blk];
        c2[l] = cb2[l] + M2[(size_t)l * NBLK + blk];
    }
    __syncthreads();
    int base = blk * CH;
    int lim = min(E - base, CH);
    for (int j = threadIdx.x; j < lim; j += BTL) {
        int s = src[base + j], d = dst[base + j];
        int p = atomicAdd(&c1[d >> LOGC], 1);
        PC[p] = ((unsigned int)s << LOGC) | (unsigned int)(d & (CNPB - 1));
        int q = atomicAdd(&c2[s >> LOGC], 1);
        SC[q] = s;
    }
}

// Out-degrees: one block per coarse src bucket, 4096-counter LDS histogram.
__global__ void sdegC_kernel(const int* __restrict__ SC, const int* __restrict__ cb2,
                             const float* __restrict__ x,
                             float* __restrict__ ns, float* __restrict__ sx, int N) {
    __shared__ int h[CNPB];
    int b = blockIdx.x;
    for (int l = threadIdx.x; l < CNPB; l += BTL) h[l] = 0;
    __syncthreads();
    int gb = cb2[b], ge = cb2[b + 1];
    for (int j = gb + threadIdx.x; j < ge; j += BTL) atomicAdd(&h[SC[j] & (CNPB - 1)], 1);
    __syncthreads();
    int vb = b << LOGC;
    for (int l = threadIdx.x; l < CNPB; l += BTL) {
        int v = vb + l;
        if (v < N) {
            int d = h[l];
            float nsv = d > 0 ? rsqrtf((float)d) : 0.f;
            ns[v] = nsv;
            sx[v] = x[v] * nsv;
        }
    }
}

// Fine pass: one block per coarse dst bucket. Two-pass 64-bin counting sort:
// bin = (fine_dst 3 bits)<<3 | (src stripe = top 3 bits of src).
// Emits P = (src<<9)|dst_local9 ordered by (fine_dst, stripe), and bbase1.
__global__ void fine_kernel(const unsigned int* __restrict__ PC, const int* __restrict__ cb1,
                            unsigned int* __restrict__ P, int* __restrict__ bbase1) {
    __shared__ int h[NBIN];
    __shared__ int cur[NBIN];
    int b = blockIdx.x;
    int gb = cb1[b], ge = cb1[b + 1];
    int t = threadIdx.x;
    if (t < NBIN) h[t] = 0;
    __syncthreads();
    for (int j = gb + t; j < ge; j += BTL) {
        unsigned int val = PC[j];
        int bin = (int)(((val >> LOGW) & 7u) << 3) | (int)(val >> 29);
        atomicAdd(&h[bin], 1);
    }
    __syncthreads();
    if (t < 64) {               // one wave: exclusive scan of 64 bins
        int v = h[t];
        int s = v;
        #pragma unroll
        for (int o = 1; o < 64; o <<= 1) { int u = __shfl_up(s, o); if (t >= o) s += u; }
        int excl = s - v;
        cur[t] = gb + excl;
        if ((t & 7) == 0) bbase1[b * 8 + (t >> 3)] = gb + excl;
    }
    __syncthreads();
    for (int j = gb + t; j < ge; j += BTL) {
        unsigned int val = PC[j];
        int bin = (int)(((val >> LOGW) & 7u) << 3) | (int)(val >> 29);
        int p = atomicAdd(&cur[bin], 1);
        P[p] = ((val >> LOGC) << LOGW) | (val & (NPB - 1));
    }
}

// ---------------- fused gathers (NPB = 512, 4x-unrolled) ----------------

__global__ void g1_kernel(const unsigned int* __restrict__ P, const int* __restrict__ bbase1,
                          const float* __restrict__ sx, const float* __restrict__ ns,
                          float* __restrict__ nd,
                          const float* __restrict__ W1, const float* __restrict__ b1,
                          const float* __restrict__ W2, float4* __restrict__ A, int N) {
    __shared__ float acc[NPB];
    __shared__ int cnt[NPB];
    int b = blockIdx.x;
    for (int l = threadIdx.x; l < NPB; l += BT) { acc[l] = 0.f; cnt[l] = 0; }
    __syncthreads();
    int gb = bbase1[b], ge = bbase1[b + 1];
    int j = gb + threadIdx.x;
    for (; j + 3 * BT < ge; j += 4 * BT) {
        unsigned int v0 = P[j], v1 = P[j + BT], v2 = P[j + 2 * BT], v3 = P[j + 3 * BT];
        float s0 = sx[v0 >> LOGW];
        float s1 = sx[v1 >> LOGW];
        float s2 = sx[v2 >> LOGW];
        float s3 = sx[v3 >> LOGW];
        int l0 = (int)(v0 & (NPB - 1)), l1 = (int)(v1 & (NPB - 1));
        int l2 = (int)(v2 & (NPB - 1)), l3 = (int)(v3 & (NPB - 1));
        atomicAdd(&acc[l0], s0); atomicAdd(&cnt[l0], 1);
        atomicAdd(&acc[l1], s1); atomicAdd(&cnt[l1], 1);
        atomicAdd(&acc[l2], s2); atomicAdd(&cnt[l2], 1);
        atomicAdd(&acc[l3], s3); atomicAdd(&cnt[l3], 1);
    }
    for (; j < ge; j += BT) {
        unsigned int val = P[j];
        int l = (int)(val & (NPB - 1));
        atomicAdd(&acc[l], sx[val >> LOGW]);
        atomicAdd(&cnt[l], 1);
    }
    __syncthreads();
    int vb = b << LOGW;
    for (int l = threadIdx.x; l < NPB; l += BT) {
        int v = vb + l;
        if (v < N) {
            int hh = cnt[l];
            float ndv = hh > 0 ? rsqrtf((float)hh) : 0.f;
            nd[v] = ndv;
            float tt = acc[l] * ndv;
            float nsv = ns[v];
            float x0 = fmaxf(tt * W1[0] + b1[0], 0.f) * nsv;
            float x1 = fmaxf(tt * W1[1] + b1[1], 0.f) * nsv;
            float x2 = fmaxf(tt * W1[2] + b1[2], 0.f) * nsv;
            float x3 = fmaxf(tt * W1[3] + b1[3], 0.f) * nsv;
            float4 o;
            o.x = x0*W2[0] + x1*W2[4] + x2*W2[8]  + x3*W2[12];
            o.y = x0*W2[1] + x1*W2[5] + x2*W2[9]  + x3*W2[13];
            o.z = x0*W2[2] + x1*W2[6] + x2*W2[10] + x3*W2[14];
            o.w = x0*W2[3] + x1*W2[7] + x2*W2[11] + x3*W2[15];
            A[v] = o;
        }
    }
}

__global__ void g4_kernel(const unsigned int* __restrict__ P, const int* __restrict__ bbase1,
                          const float4* __restrict__ H, const float* __restrict__ ns,
                          const float* __restrict__ nd,
                          const float* __restrict__ bb, const float* __restrict__ W,
                          float4* __restrict__ out, int N) {
    __shared__ float acc[NPB * 4];
    int b = blockIdx.x;
    for (int l = threadIdx.x; l < NPB * 4; l += BT) acc[l] = 0.f;
    __syncthreads();
    int gb = bbase1[b], ge = bbase1[b + 1];
    int j = gb + threadIdx.x;
    for (; j + 3 * BT < ge; j += 4 * BT) {
        unsigned int v0 = P[j], v1 = P[j + BT], v2 = P[j + 2 * BT], v3 = P[j + 3 * BT];
        float4 h0 = H[v0 >> LOGW];
        float4 h1 = H[v1 >> LOGW];
        float4 h2 = H[v2 >> LOGW];
        float4 h3 = H[v3 >> LOGW];
        int l0 = (int)(v0 & (NPB - 1)) * 4, l1 = (int)(v1 & (NPB - 1)) * 4;
        int l2 = (int)(v2 & (NPB - 1)) * 4, l3 = (int)(v3 & (NPB - 1)) * 4;
        atomicAdd(&acc[l0+0], h0.x); atomicAdd(&acc[l0+1], h0.y);
        atomicAdd(&acc[l0+2], h0.z); atomicAdd(&acc[l0+3], h0.w);
        atomicAdd(&acc[l1+0], h1.x); atomicAdd(&acc[l1+1], h1.y);
        atomicAdd(&acc[l1+2], h1.z); atomicAdd(&acc[l1+3], h1.w);
        atomicAdd(&acc[l2+0], h2.x); atomicAdd(&acc[l2+1], h2.y);
        atomicAdd(&acc[l2+2], h2.z); atomicAdd(&acc[l2+3], h2.w);
        atomicAdd(&acc[l3+0], h3.x); atomicAdd(&acc[l3+1], h3.y);
        atomicAdd(&acc[l3+2], h3.z); atomicAdd(&acc[l3+3], h3.w);
    }
    for (; j < ge; j += BT) {
        unsigned int val = P[j];
        float4 v = H[val >> LOGW];
        int l4 = (int)(val & (NPB - 1)) * 4;
        atomicAdd(&acc[l4 + 0], v.x);
        atomicAdd(&acc[l4 + 1], v.y);
        atomicAdd(&acc[l4 + 2], v.z);
        atomicAdd(&acc[l4 + 3], v.w);
    }
    __syncthreads();
    int vb = b << LOGW;
    for (int l = threadIdx.x; l < NPB; l += BT) {
        int v = vb + l;
        if (v < N) {
            float ndv = nd[v], nsv = ns[v];
            float x0 = fmaxf(acc[l*4+0] * ndv + bb[0], 0.f) * nsv;
            float x1 = fmaxf(acc[l*4+1] * ndv + bb[1], 0.f) * nsv;
            float x2 = fmaxf(acc[l*4+2] * ndv + bb[2], 0.f) * nsv;
            float x3 = fmaxf(acc[l*4+3] * ndv + bb[3], 0.f) * nsv;
            float4 o;
            o.x = x0*W[0] + x1*W[4] + x2*W[8]  + x3*W[12];
            o.y = x0*W[1] + x1*W[5] + x2*W[9]  + x3*W[13];
            o.z = x0*W[2] + x1*W[6] + x2*W[10] + x3*W[14];
            o.w = x0*W[3] + x1*W[7] + x2*W[11] + x3*W[15];
            out[v] = o;
        }
    }
}

__global__ void gF_kernel(const unsigned int* __restrict__ P, const int* __restrict__ bbase1,
                          const float4* __restrict__ H, const float* __restrict__ nd,
                          const float* __restrict__ bb, const float* __restrict__ Wl,
                          const float* __restrict__ bl, float2* __restrict__ out, int N) {
    __shared__ float acc[NPB * 4];
    int b = blockIdx.x;
    for (int l = threadIdx.x; l < NPB * 4; l += BT) acc[l] = 0.f;
    __syncthreads();
    int gb = bbase1[b], ge = bbase1[b + 1];
    int j = gb + threadIdx.x;
    for (; j + 3 * BT < ge; j += 4 * BT) {
        unsigned int v0 = P[j], v1 = P[j + BT], v2 = P[j + 2 * BT], v3 = P[j + 3 * BT];
        float4 h0 = H[v0 >> LOGW];
        float4 h1 = H[v1 >> LOGW];
        float4 h2 = H[v2 >> LOGW];
        float4 h3 = H[v3 >> LOGW];
        int l0 = (int)(v0 & (NPB - 1)) * 4, l1 = (int)(v1 & (NPB - 1)) * 4;
        int l2 = (int)(v2 & (NPB - 1)) * 4, l3 = (int)(v3 & (NPB - 1)) * 4;
        atomicAdd(&acc[l0+0], h0.x); atomicAdd(&acc[l0+1], h0.y);
        atomicAdd(&acc[l0+2], h0.z); atomicAdd(&acc[l0+3], h0.w);
        atomicAdd(&acc[l1+0], h1.x); atomicAdd(&acc[l1+1], h1.y);
        atomicAdd(&acc[l1+2], h1.z); atomicAdd(&acc[l1+3], h1.w);
        atomicAdd(&acc[l2+0], h2.x); atomicAdd(&acc[l2+1], h2.y);
        atomicAdd(&acc[l2+2], h2.z); atomicAdd(&acc[l2+3], h2.w);
        atomicAdd(&acc[l3+0], h3.x); atomicAdd(&acc[l3+1], h3.y);
        atomicAdd(&acc[l3+2], h3.z); atomicAdd(&acc[l3+3], h3.w);
    }
    for (; j < ge; j += BT) {
        unsigned int val = P[j];
        float4 v = H[val >> LOGW];
        int l4 = (int)(val & (NPB - 1)) * 4;
        atomicAdd(&acc[l4 + 0], v.x);
        atomicAdd(&acc[l4 + 1], v.y);
        atomicAdd(&acc[l4 + 2], v.z);
        atomicAdd(&acc[l4 + 3], v.w);
    }
    __syncthreads();
    int vb = b << LOGW;
    for (int l = threadIdx.x; l < NPB; l += BT) {
        int v = vb + l;
        if (v < N) {
            float ndv = nd[v];
            float x0 = acc[l*4+0] * ndv + bb[0];
            float x1 = acc[l*4+1] * ndv + bb[1];
            float x2 = acc[l*4+2] * ndv + bb[2];
            float x3 = acc[l*4+3] * ndv + bb[3];
            float z0 = x0*Wl[0] + x1*Wl[2] + x2*Wl[4] + x3*Wl[6] + bl[0];
            float z1 = x0*Wl[1] + x1*Wl[3] + x2*Wl[5] + x3*Wl[7] + bl[1];
            float m  = fmaxf(z0, z1);
            float e0 = expf(z0 - m), e1 = expf(z1 - m);
            float inv = 1.f / (e0 + e1);
            out[v] = make_float2(e0 * inv, e1 * inv);
        }
    }
}

// ---------------- round-2 fallback (atomic-cursor CSR) ----------------

__global__ void count_kernel(const int* __restrict__ src, const int* __restrict__ dst,
                             int* __restrict__ degs, int* __restrict__ degd, int E) {
    int i = blockIdx.x * blockDim.x + threadIdx.x;
    if (i < E) { atomicAdd(&degs[src[i]], 1); atomicAdd(&degd[dst[i]], 1); }
}

__global__ void finalize_alloc_kernel(const int* __restrict__ degs, const int* __restrict__ degd,
                                      const float* __restrict__ x,
                                      float* __restrict__ ns, float* __restrict__ nd,
                                      float* __restrict__ sx, int* __restrict__ start,
                                      int* __restrict__ cursor, int N) {
    int i = blockIdx.x * blockDim.x + threadIdx.x;
    int lane = threadIdx.x & 63;
    int dd = 0;
    if (i < N) {
        int ds = degs[i];
        float nsv = ds > 0 ? rsqrtf((float)ds) : 0.f;
        ns[i] = nsv;
        dd = degd[i];
        nd[i] = dd > 0 ? rsqrtf((float)dd) : 0.f;
        sx[i] = x[i] * nsv;
    }
    int pre = dd;
    #pragma unroll
    for (int off = 1; off < 64; off <<= 1) {
        int t = __shfl_up(pre, off);
        if (lane >= off) pre += t;
    }
    int total = __shfl(pre, 63);
    int base = 0;
    if (lane == 63 && total > 0) base = atomicAdd(cursor, total);
    base = __shfl(base, 63);
    if (i < N) start[i] = base + pre - dd;
}

__global__ void fill_kernel(const int* __restrict__ src, const int* __restrict__ dst,
                            int* __restrict__ start, int* __restrict__ eidx, int E) {
    int i = blockIdx.x * blockDim.x + threadIdx.x;
    if (i < E) {
        int p = atomicAdd(&start[dst[i]], 1);
        eidx[p] = src[i];
    }
}

__global__ void fb_g1(const float* __restrict__ sx, const int* __restrict__ eidx,
                      const int* __restrict__ endp, const int* __restrict__ deg,
                      const float* __restrict__ ns, const float* __restrict__ nd,
                      const float* __restrict__ W1, const float* __restrict__ b1,
                      const float* __restrict__ W2, float4* __restrict__ A, int N) {
    int i = blockIdx.x * blockDim.x + threadIdx.x;
    if (i >= N) return;
    int e = endp[i], d = deg[i];
    float sum = 0.f;
    for (int k = e - d; k < e; ++k) sum += sx[eidx[k]];
    float t = sum * nd[i];
    float nsv = ns[i];
    float x0 = fmaxf(t * W1[0] + b1[0], 0.f) * nsv;
    float x1 = fmaxf(t * W1[1] + b1[1], 0.f) * nsv;
    float x2 = fmaxf(t * W1[2] + b1[2], 0.f) * nsv;
    float x3 = fmaxf(t * W1[3] + b1[3], 0.f) * nsv;
    float4 o;
    o.x = x0*W2[0] + x1*W2[4] + x2*W2[8]  + x3*W2[12];
    o.y = x0*W2[1] + x1*W2[5] + x2*W2[9]  + x3*W2[13];
    o.z = x0*W2[2] + x1*W2[6] + x2*W2[10] + x3*W2[14];
    o.w = x0*W2[3] + x1*W2[7] + x2*W2[11] + x3*W2[15];
    A[i] = o;
}

__global__ void fb_g4(const float4* __restrict__ H, const int* __restrict__ eidx,
                      const int* __restrict__ endp, const int* __restrict__ deg,
                      const float* __restrict__ ns, const float* __restrict__ nd,
                      const float* __restrict__ b, const float* __restrict__ W,
                      float4* __restrict__ out, int N) {
    int i = blockIdx.x * blockDim.x + threadIdx.x;
    if (i >= N) return;
    int e = endp[i], d = deg[i];
    float s0 = 0.f, s1 = 0.f, s2 = 0.f, s3 = 0.f;
    for (int k = e - d; k < e; ++k) {
        float4 v = H[eidx[k]];
        s0 += v.x; s1 += v.y; s2 += v.z; s3 += v.w;
    }
    float nv = nd[i], nsv = ns[i];
    float x0 = fmaxf(s0 * nv + b[0], 0.f) * nsv;
    float x1 = fmaxf(s1 * nv + b[1], 0.f) * nsv;
    float x2 = fmaxf(s2 * nv + b[2], 0.f) * nsv;
    float x3 = fmaxf(s3 * nv + b[3], 0.f) * nsv;
    float4 o;
    o.x = x0*W[0] + x1*W[4] + x2*W[8]  + x3*W[12];
    o.y = x0*W[1] + x1*W[5] + x2*W[9]  + x3*W[13];
    o.z = x0*W[2] + x1*W[6] + x2*W[10] + x3*W[14];
    o.w = x0*W[3] + x1*W[7] + x2*W[11] + x3*W[15];
    out[i] = o;
}

__global__ void fb_gF(const float4* __restrict__ H, const int* __restrict__ eidx,
                      const int* __restrict__ endp, const int* __restrict__ deg,
                      const float* __restrict__ nd, const float* __restrict__ b,
                      const float* __restrict__ Wl, const float* __restrict__ bl,
                      float2* __restrict__ out, int N) {
    int i = blockIdx.x * blockDim.x + threadIdx.x;
    if (i >= N) return;
    int e = endp[i], d = deg[i];
    float s0 = 0.f, s1 = 0.f, s2 = 0.f, s3 = 0.f;
    for (int k = e - d; k < e; ++k) {
        float4 v = H[eidx[k]];
        s0 += v.x; s1 += v.y; s2 += v.z; s3 += v.w;
    }
    float nv = nd[i];
    float x0 = s0 * nv + b[0];
    float x1 = s1 * nv + b[1];
    float x2 = s2 * nv + b[2];
    float x3 = s3 * nv + b[3];
    float z0 = x0*Wl[0] + x1*Wl[2] + x2*Wl[4] + x3*Wl[6] + bl[0];
    float z1 = x0*Wl[1] + x1*Wl[3] + x2*Wl[5] + x3*Wl[7] + bl[1];
    float m  = fmaxf(z0, z1);
    float e0 = expf(z0 - m), e1 = expf(z1 - m);
    float inv = 1.f / (e0 + e1);
    out[i] = make_float2(e0 * inv, e1 * inv);
}

extern "C" void kernel_launch(void* const* d_in, const int* in_sizes, int n_in,
                              void* d_out, int out_size, void* d_ws, size_t ws_size,
                              hipStream_t stream) {
    const float* in_feat = (const float*)d_in[0];
    const int*   src     = (const int*)d_in[1];
    const int*   dst     = (const int*)d_in[2];
    const float* W1 = (const float*)d_in[3];
    const float* b1 = (const float*)d_in[4];
    const float* W2 = (const float*)d_in[5];
    const float* b2 = (const float*)d_in[6];
    const float* W3 = (const float*)d_in[7];
    const float* b3 = (const float*)d_in[8];
    const float* Wl = (const float*)d_in[9];
    const float* bl = (const float*)d_in[10];

    const int N = in_sizes[0];
    const int E = in_sizes[1];

    const int gridN = (N + BT - 1) / BT;
    const int gridE = (E + BT - 1) / BT;

    const int KC   = (N + CNPB - 1) >> LOGC;     // coarse buckets
    const int K    = (N + NPB - 1) >> LOGW;      // fine buckets
    const int NBLK = (E + CH - 1) / CH;
    const size_t uN = (size_t)N, uE = (size_t)E;

    // Workspace (4B units):
    //  ns[N] | nd[N] (M1,M2 alias here until g1) | sx[N] | ctr[3104]
    //  | R1[max(E,8N)]  (PC, then A(4N)+B(4N))
    //  | R2[E]          (SC, then P)
    const size_t CTRI = 257 * 4 + 8 * (size_t)KCMAX + 8;
    const size_t r1 = (uE > 8 * uN) ? uE : 8 * uN;
    const size_t need6 = (3 * uN + CTRI + r1 + uE) * 4;

    const bool ok6 = (ws_size >= need6) && (N <= (1 << 20)) && (KC <= KCMAX)
                     && (2 * (size_t)KC * NBLK <= uN);

    if (ok6) {
        float* ws   = (float*)d_ws;
        float* ns   = ws;
        float* nd   = ws + uN;
        float* sx   = ws + 2 * uN;
        int*   ctr  = (int*)(ws + 3 * uN);
        int* bs1    = ctr;
        int* bs2    = ctr + 257;
        int* cb1    = ctr + 514;
        int* cb2    = ctr + 771;
        int* bbase1 = ctr + 1028;
        int*   R1   = (int*)(ws + 3 * uN + CTRI);
        int*   R2   = R1 + r1;
        int*   M1   = (int*)nd;                  // dead until g1 writes nd
        int*   M2   = M1 + (size_t)KC * NBLK;
        unsigned int* PC = (unsigned int*)R1;
        int*   SC   = R2;
        unsigned int* P  = (unsigned int*)R2;    // fine pass overwrites SC
        float4* A   = (float4*)R1;               // PC dead after fine
        float4* B4  = (float4*)(R1 + 4 * uN);

        histC_kernel<<<NBLK, BTL, 0, stream>>>(src, dst, M1, M2, E, KC, NBLK);
        rowscan_kernel<<<KC, 64, 0, stream>>>(M1, M2, bs1, bs2, NBLK);
        scanC_kernel<<<1, 256, 0, stream>>>(bs1, cb1, bs2, cb2, bbase1, KC);
        rankC_kernel<<<NBLK, BTL, 0, stream>>>(src, dst, M1, M2, cb1, cb2, PC, SC, E, KC, NBLK);
        sdegC_kernel<<<KC, BTL, 0, stream>>>(SC, cb2, in_feat, ns, sx, N);
        fine_kernel<<<KC, BTL, 0, stream>>>(PC, cb1, P, bbase1);
        g1_kernel<<<K, BT, 0, stream>>>(P, bbase1, sx, ns, nd, W1, b1, W2, A, N);
        g4_kernel<<<K, BT, 0, stream>>>(P, bbase1, A, ns, nd, b2, W3, B4, N);
        gF_kernel<<<K, BT, 0, stream>>>(P, bbase1, B4, nd, b3, Wl, bl, (float2*)d_out, N);
        return;
    }

    // ---------- round-2 fallback ----------
    size_t need2 = (13 * uN + uE + 16) * 4;
    if (ws_size >= need2) {
        float* ws   = (float*)d_ws;
        float* ns   = ws;
        float* nd   = ws + uN;
        float* sx   = ws + 2 * uN;
        int*   deg  = (int*)(ws + 3 * uN);
        int*   start= (int*)(ws + 4 * uN);
        float4* A   = (float4*)(ws + 5 * uN);
        float4* B   = (float4*)(ws + 9 * uN);
        int*   eidx = (int*)(ws + 13 * uN);
        int*   cursor = eidx + uE;
        int*   degs = (int*)A;

        hipMemsetAsync(deg, 0, uN * sizeof(int), stream);
        hipMemsetAsync(degs, 0, uN * sizeof(int), stream);
        hipMemsetAsync(cursor, 0, sizeof(int), stream);
        count_kernel<<<gridE, BT, 0, stream>>>(src, dst, degs, deg, E);
        finalize_alloc_kernel<<<gridN, BT, 0, stream>>>(degs, deg, in_feat, ns, nd, sx, start, cursor, N);
        fill_kernel<<<gridE, BT, 0, stream>>>(src, dst, start, eidx, E);
        fb_g1<<<gridN, BT, 0, stream>>>(sx, eidx, start, deg, ns, nd, W1, b1, W2, A, N);
        fb_g4<<<gridN, BT, 0, stream>>>(A, eidx, start, deg, ns, nd, b2, W3, B, N);
        fb_gF<<<gridN, BT, 0, stream>>>(B, eidx, start, deg, nd, b3, Wl, bl, (float2*)d_out, N);
    }
}